// Round 2
// baseline (3165.099 us; speedup 1.0000x reference)
//
#include <hip/hip_runtime.h>
#include <hip/hip_bf16.h>

#define DI __device__ __forceinline__

typedef __bf16 bf16x8 __attribute__((ext_vector_type(8)));
typedef __bf16 bf16x4 __attribute__((ext_vector_type(4)));
typedef __bf16 bf16x2 __attribute__((ext_vector_type(2)));
typedef float  f32x4  __attribute__((ext_vector_type(4)));
typedef unsigned long long ull;

static constexpr int Bc = 64, Tc = 256, Ic = 128, Hc = 512, Oc = 64;
static constexpr int TBc = Tc * Bc;                 // 16384
static constexpr size_t THW = (size_t)TBc * Hc;     // 8388608 elems

// ---------- d_out offsets (floats) ----------
static constexpr size_t O_OUT = 0;
static constexpr size_t O_HT  = 4096;
static constexpr size_t O_DW0 = 36864;
static constexpr size_t O_DV0 = 823296;
static constexpr size_t O_DB0 = 1019904;
static constexpr size_t O_ERR = 1021440;

// ---------- ws offsets (bytes) ----------
static constexpr size_t W_CTR  = 0;        // legacy counter region (unused)
static constexpr size_t W_SLOT = 1024;     // 9 f32
static constexpr size_t W_DB   = 2048;     // db_raw [3][512] f32 -> ends 8192
static constexpr size_t W_FLG  = 8192;     // barrier epoch flags: 64 slots x 128B -> ends 16384
static constexpr size_t W_ERRW = 16384;    // error [64][64] f32
static constexpr size_t W_PROJ = 32768;    // proj [6][64][512] f32 -> ends 819200
static constexpr size_t W_W1B  = 819200;   // W1 bf16 [512][512] -> ends 1343488
static constexpr size_t W_HX   = 1343488;  // h exchange fp32 [4][8192] (128 KB)
static constexpr size_t W_HRX  = 1474560;  // hr exchange fp32 [4][8192] -> ends 1605632
static constexpr size_t W_XT   = 1605632;  // x^T bf16 [128][TB] -> ends 5799936
static constexpr size_t W_HIST = 5799936;  // r,z,ht,h bf16 [TB][512] each -> ends 72908800
static constexpr size_t W_PB   = 72908800; // xV fp32 (100.6MB) / later P + HpT + RsHpT
static constexpr size_t W_NEED = W_PB + 100663296;   // 173572096

// =========================== helpers ===========================

DI void st32_agent(float* p, float v) {
  __hip_atomic_store((unsigned int*)p, __float_as_uint(v),
                     __ATOMIC_RELAXED, __HIP_MEMORY_SCOPE_AGENT);
}
DI ull ld64_agent(const void* p) {
  return __hip_atomic_load((ull*)p, __ATOMIC_RELAXED, __HIP_MEMORY_SCOPE_AGENT);
}

// Fence-free group barrier via distributed epoch flags. Each wg STORES the
// epoch to its own 128B-strided slot (no RMW); wave 0 polls all 16 slots with
// 16 parallel lanes. The leading __syncthreads() emits s_waitcnt vmcnt(0) per
// wave, draining the agent-scope exchange stores before the flag store.
DI void group_barrier(int* flags_g, int myslot, int bar, bool& dead) {
  __syncthreads();
  if (threadIdx.x == 0)
    __hip_atomic_store(&flags_g[myslot * 32], bar,
                       __ATOMIC_RELAXED, __HIP_MEMORY_SCOPE_AGENT);
  if (threadIdx.x < 64 && !dead) {
    const int l = threadIdx.x;
    int spins = 0;
    for (;;) {
      int v = bar;
      if (l < 16)
        v = __hip_atomic_load(&flags_g[l * 32],
                              __ATOMIC_RELAXED, __HIP_MEMORY_SCOPE_AGENT);
      if (__all(v >= bar)) break;
      __builtin_amdgcn_s_sleep(1);
      if (++spins > 4000000) { dead = true; break; }   // never hang the bench
    }
  }
  __syncthreads();
}

// hiddens[t-1] with python-negative-index quirk; k = t*64+b
DI float hprev_at(const __bf16* __restrict__ h_h, int k, int col) {
  int t = k >> 6;
  if (t == 1) return 0.f;
  int row = (t == 0) ? (16320 + (k & 63)) : (k - 128);
  return (float)h_h[(size_t)row * 512 + col];
}

// =========================== tiny kernels ===========================

__global__ void kzero(float* __restrict__ p, int n) {
  int i = blockIdx.x * 256 + threadIdx.x;
  if (i < n) p[i] = 0.f;
}
__global__ void ksent(float* p, float v) { p[0] = v; }
__global__ void k0_cast(const float* __restrict__ s, __bf16* __restrict__ d, int n) {
  int i = blockIdx.x * 256 + threadIdx.x;
  if (i < n) d[i] = (__bf16)s[i];
}

// =========================== K1: xV = x@V^T + bias (fp32) ===========================
__global__ __launch_bounds__(256)
void k1_xv(const float* __restrict__ x, const float* __restrict__ V1w,
           const float* __restrict__ V2w, const float* __restrict__ V3w,
           const float* __restrict__ V1b, const float* __restrict__ W2b,
           const float* __restrict__ W3b,
           float* __restrict__ xv1f, float* __restrict__ xv2f, float* __restrict__ xv3f)
{
  const int cb = blockIdx.x, t = blockIdx.y;
  const int g = cb >> 3, jblk = cb & 7;
  const float* Vg   = (g == 0) ? V1w : (g == 1) ? V2w : V3w;
  const float* bias = (g == 0) ? V1b : (g == 1) ? W2b : W3b;
  float* of = (g == 0) ? xv1f : (g == 1) ? xv2f : xv3f;
  __shared__ float As[64 * 69];
  __shared__ float Bs[64 * 69];
  const int tid = threadIdx.x;
  float acc[4][4] = {};
  const int m0 = (tid & 15) * 4, j0 = (tid >> 4) * 4;
  for (int kc = 0; kc < 2; ++kc) {
    __syncthreads();
    #pragma unroll
    for (int e = 0; e < 4; ++e) {
      int idx = tid + e * 256;            // 0..1023
      int row = idx >> 4, c4 = (idx & 15) * 4;
      float4 v = *reinterpret_cast<const float4*>(&x[((size_t)row * 256 + t) * 128 + kc * 64 + c4]);
      As[row * 69 + c4 + 0] = v.x; As[row * 69 + c4 + 1] = v.y;
      As[row * 69 + c4 + 2] = v.z; As[row * 69 + c4 + 3] = v.w;
      float4 w = *reinterpret_cast<const float4*>(&Vg[(size_t)(jblk * 64 + row) * 128 + kc * 64 + c4]);
      Bs[row * 69 + c4 + 0] = w.x; Bs[row * 69 + c4 + 1] = w.y;
      Bs[row * 69 + c4 + 2] = w.z; Bs[row * 69 + c4 + 3] = w.w;
    }
    __syncthreads();
    for (int i = 0; i < 64; ++i) {
      float a[4], b[4];
      #pragma unroll
      for (int u = 0; u < 4; ++u) a[u] = As[(m0 + u) * 69 + i];
      #pragma unroll
      for (int u = 0; u < 4; ++u) b[u] = Bs[(j0 + u) * 69 + i];
      #pragma unroll
      for (int mi = 0; mi < 4; ++mi)
        #pragma unroll
        for (int ji = 0; ji < 4; ++ji) acc[mi][ji] += a[mi] * b[ji];
    }
  }
  #pragma unroll
  for (int ji = 0; ji < 4; ++ji) {
    int jg = jblk * 64 + j0 + ji;
    float bv = bias[jg];
    #pragma unroll
    for (int mi = 0; mi < 4; ++mi) {
      int b = m0 + mi;
      of[((size_t)t * 64 + b) * 512 + jg] = acc[mi][ji] + bv;
    }
  }
}

// =========================== E0: X^T bf16 [128][TB] ===========================
__global__ void e0_xt(const float* __restrict__ x, __bf16* __restrict__ XT)
{
  const int t = blockIdx.x;
  __shared__ __bf16 xs[64 * 132];
  const int tid = threadIdx.x;
  #pragma unroll
  for (int e = 0; e < 8; ++e) {
    int idx = tid + e * 256;              // 0..2047
    int b = idx >> 5, c4 = (idx & 31) * 4;
    float4 v = *reinterpret_cast<const float4*>(&x[((size_t)b * 256 + t) * 128 + c4]);
    xs[b * 132 + c4 + 0] = (__bf16)v.x; xs[b * 132 + c4 + 1] = (__bf16)v.y;
    xs[b * 132 + c4 + 2] = (__bf16)v.z; xs[b * 132 + c4 + 3] = (__bf16)v.w;
  }
  __syncthreads();
  #pragma unroll
  for (int e = 0; e < 8; ++e) {
    int idx = tid + e * 256;
    int i = idx >> 4, b4 = (idx & 15) * 4;
    __bf16* d = &XT[(size_t)i * TBc + t * 64 + b4];
    d[0] = xs[(b4 + 0) * 132 + i];
    d[1] = xs[(b4 + 1) * 132 + i];
    d[2] = xs[(b4 + 2) * 132 + i];
    d[3] = xs[(b4 + 3) * 132 + i];
  }
}

// =========================== K2: persistent GRU recurrence, fp32-faithful =========
// 64 wgs = 4 batch-groups(16 rows) x 16 col-wgs(32 cols). 8 waves/wg (512 thr)
// = 2 col-tiles x 4 k-quarters (4 kk each). 2 waves/SIMD -> TLP hides MFMA
// latency; per-thread weight frags = 144 VGPR (no spills). Both operands split
// 3-way bf16 (Ootomo 6-term MFMA). h exchanged fp32; exchange layout == LDS
// fragment layout (identity), lane-consecutive 8B loads, 4B-stride ds_writes.
__global__ __launch_bounds__(512, 1)
void k2_recur(const float* __restrict__ W1w, const float* __restrict__ W2w,
              const float* __restrict__ W3w,
              const float* __restrict__ xv1, const float* __restrict__ xv2,
              const float* __restrict__ xv3,
              __bf16* __restrict__ r_h, __bf16* __restrict__ z_h,
              __bf16* __restrict__ ht_h, __bf16* __restrict__ h_h,
              float* __restrict__ hx, float* __restrict__ hrx,
              int* __restrict__ flags, float* __restrict__ dout)
{
  const int g  = blockIdx.x >> 4;      // batch group 0..3
  const int cw = blockIdx.x & 15;      // col-wg 0..15
  const int tid = threadIdx.x, lane = tid & 63, wv = tid >> 6;
  const int ks = wv & 3;               // k-quarter 0..3
  const int ct = wv >> 2;              // col-tile 0..1
  const int q  = lane >> 4;
  const int colc = cw * 32 + ct * 16 + (lane & 15);
  const bool owner = (ks == 0);

  __shared__ __align__(16) __bf16 c0[8192];   // h comp0 frags [16kk][64lane][8]
  __shared__ __align__(16) __bf16 c1[8192];
  __shared__ __align__(16) __bf16 c2[8192];
  __shared__ float pbuf[3 * 128 * 8];         // cross-wave k-partials (3 slots)

  // weight fragments, 3-way split: lane n=colc, k = (ks*4+kk2)*32 + q*8 + j
  bf16x8 w1c[3][4], w2c[3][4], w3c[3][4];
  #pragma unroll
  for (int kk2 = 0; kk2 < 4; ++kk2) {
    const int kb = (ks * 4 + kk2) * 32 + q * 8;
    #pragma unroll
    for (int j = 0; j < 8; ++j) {
      float w = W1w[(size_t)colc * 512 + kb + j];
      __bf16 a = (__bf16)w; float r1 = w - (float)a;
      __bf16 b = (__bf16)r1;
      w1c[0][kk2][j] = a; w1c[1][kk2][j] = b; w1c[2][kk2][j] = (__bf16)(r1 - (float)b);
      w = W2w[(size_t)colc * 512 + kb + j];
      a = (__bf16)w; r1 = w - (float)a; b = (__bf16)r1;
      w2c[0][kk2][j] = a; w2c[1][kk2][j] = b; w2c[2][kk2][j] = (__bf16)(r1 - (float)b);
      w = W3w[(size_t)colc * 512 + kb + j];
      a = (__bf16)w; r1 = w - (float)a; b = (__bf16)r1;
      w3c[0][kk2][j] = a; w3c[1][kk2][j] = b; w3c[2][kk2][j] = (__bf16)(r1 - (float)b);
    }
  }
  for (int i = tid; i < 8192; i += 512) {
    c0[i] = (__bf16)0.f; c1[i] = (__bf16)0.f; c2[i] = (__bf16)0.f;
  }
  __syncthreads();

  float hreg[4] = {0.f, 0.f, 0.f, 0.f};
  float* hx_g  = hx  + g * 8192;
  float* hrx_g = hrx + g * 8192;
  int* flags_g = flags + g * 16 * 32;
  // frag index for state element (m=q*4+i, c=colc)
  const int fragbase = (colc >> 5) * 512 + (((colc >> 3) & 3) * 16 + q * 4) * 8 + (colc & 7);
  const int pb = (ct * 64 + lane) * 8;

  // coalesced exchange reload: lane-consecutive ull loads, identity map to
  // the c0/c1/c2 fragment layout (LDS byte offset = 4 * ull index).
  auto stage = [&](const float* __restrict__ srcf) {
    const ull* src = reinterpret_cast<const ull*>(srcf);
    ull u[8];
    #pragma unroll
    for (int j = 0; j < 8; ++j) u[j] = ld64_agent(src + j * 512 + tid);
    #pragma unroll
    for (int j = 0; j < 8; ++j) {
      float f0 = __uint_as_float((unsigned int)u[j]);
      float f1 = __uint_as_float((unsigned int)(u[j] >> 32));
      __bf16 a0 = (__bf16)f0; float r0 = f0 - (float)a0; __bf16 b0 = (__bf16)r0;
      __bf16 d0 = (__bf16)(r0 - (float)b0);
      __bf16 a1 = (__bf16)f1; float r1 = f1 - (float)a1; __bf16 b1 = (__bf16)r1;
      __bf16 d1 = (__bf16)(r1 - (float)b1);
      int o = (j * 512 + tid) * 2;
      bf16x2 v0; v0[0] = a0; v0[1] = a1;
      bf16x2 v1; v1[0] = b0; v1[1] = b1;
      bf16x2 v2; v2[0] = d0; v2[1] = d1;
      *reinterpret_cast<bf16x2*>(&c0[o]) = v0;
      *reinterpret_cast<bf16x2*>(&c1[o]) = v1;
      *reinterpret_cast<bf16x2*>(&c2[o]) = v2;
    }
  };

  auto rowbase = [&](int t) -> size_t {
    return ((size_t)t * 64 + g * 16 + q * 4) * 512 + colc;
  };

  bool dead = false;
  int bar = 0;
  // preload xV for t=0
  float xv1v[4], xv2v[4], xv3v[4];
  if (owner) {
    size_t r0 = rowbase(0);
    #pragma unroll
    for (int i = 0; i < 4; ++i) {
      size_t o = r0 + (size_t)i * 512;
      xv1v[i] = xv1[o]; xv2v[i] = xv2[o]; xv3v[i] = xv3[o];
    }
  }
  #pragma unroll 1
  for (int t = 0; t < Tc; ++t) {
    const size_t rowb = rowbase(t);
    // prefetch next step's xV (drains at next syncthreads, hidden by phase 1)
    float xn1[4], xn2[4], xn3[4];
    if (owner && t + 1 < Tc) {
      size_t rn = rowbase(t + 1);
      #pragma unroll
      for (int i = 0; i < 4; ++i) {
        size_t o = rn + (size_t)i * 512;
        xn1[i] = xv1[o]; xn2[i] = xv2[o]; xn3[i] = xv3[o];
      }
    }
    // ---- phase 1: z, r gates (dual accumulation chains per gate) ----
    f32x4 a2a = {0.f,0.f,0.f,0.f}, a2b = {0.f,0.f,0.f,0.f};
    f32x4 a3a = {0.f,0.f,0.f,0.f}, a3b = {0.f,0.f,0.f,0.f};
    #pragma unroll
    for (int kk2 = 0; kk2 < 4; ++kk2) {
      const int idx = (ks * 4 + kk2) * 512 + lane * 8;
      bf16x8 h0 = *reinterpret_cast<const bf16x8*>(&c0[idx]);
      bf16x8 h1 = *reinterpret_cast<const bf16x8*>(&c1[idx]);
      bf16x8 h2 = *reinterpret_cast<const bf16x8*>(&c2[idx]);
      a2a = __builtin_amdgcn_mfma_f32_16x16x32_bf16(h0, w2c[0][kk2], a2a, 0, 0, 0);
      a2b = __builtin_amdgcn_mfma_f32_16x16x32_bf16(h1, w2c[0][kk2], a2b, 0, 0, 0);
      a2a = __builtin_amdgcn_mfma_f32_16x16x32_bf16(h0, w2c[1][kk2], a2a, 0, 0, 0);
      a2b = __builtin_amdgcn_mfma_f32_16x16x32_bf16(h2, w2c[0][kk2], a2b, 0, 0, 0);
      a2a = __builtin_amdgcn_mfma_f32_16x16x32_bf16(h1, w2c[1][kk2], a2a, 0, 0, 0);
      a2b = __builtin_amdgcn_mfma_f32_16x16x32_bf16(h0, w2c[2][kk2], a2b, 0, 0, 0);
      a3a = __builtin_amdgcn_mfma_f32_16x16x32_bf16(h0, w3c[0][kk2], a3a, 0, 0, 0);
      a3b = __builtin_amdgcn_mfma_f32_16x16x32_bf16(h1, w3c[0][kk2], a3b, 0, 0, 0);
      a3a = __builtin_amdgcn_mfma_f32_16x16x32_bf16(h0, w3c[1][kk2], a3a, 0, 0, 0);
      a3b = __builtin_amdgcn_mfma_f32_16x16x32_bf16(h2, w3c[0][kk2], a3b, 0, 0, 0);
      a3a = __builtin_amdgcn_mfma_f32_16x16x32_bf16(h1, w3c[1][kk2], a3a, 0, 0, 0);
      a3b = __builtin_amdgcn_mfma_f32_16x16x32_bf16(h0, w3c[2][kk2], a3b, 0, 0, 0);
    }
    if (!owner) {
      #pragma unroll
      for (int i = 0; i < 4; ++i) {
        pbuf[(ks - 1) * 1024 + pb + i]     = a2a[i] + a2b[i];
        pbuf[(ks - 1) * 1024 + pb + 4 + i] = a3a[i] + a3b[i];
      }
    }
    __syncthreads();
    float zz[4], rr4[4];
    if (owner) {
      #pragma unroll
      for (int i = 0; i < 4; ++i) {
        float s2 = a2a[i] + a2b[i] + pbuf[pb + i] + pbuf[1024 + pb + i]
                 + pbuf[2048 + pb + i] + xv2v[i];
        float s3 = a3a[i] + a3b[i] + pbuf[pb + 4 + i] + pbuf[1024 + pb + 4 + i]
                 + pbuf[2048 + pb + 4 + i] + xv3v[i];
        zz[i]  = 1.f / (1.f + expf(-s2));
        rr4[i] = 1.f / (1.f + expf(-s3));
        st32_agent(&hrx_g[fragbase + i * 8], hreg[i] * rr4[i]);
      }
    }
    ++bar; group_barrier(flags_g, cw, bar, dead);
    // history stores AFTER the flag (their drain overlaps consumers' stage)
    if (owner) {
      #pragma unroll
      for (int i = 0; i < 4; ++i) {
        z_h[rowb + (size_t)i * 512] = (__bf16)zz[i];
        r_h[rowb + (size_t)i * 512] = (__bf16)rr4[i];
      }
    }
    stage(hrx_g);
    __syncthreads();
    // ---- phase 2: candidate + update (dual chains) ----
    f32x4 a1a = {0.f,0.f,0.f,0.f}, a1b = {0.f,0.f,0.f,0.f};
    #pragma unroll
    for (int kk2 = 0; kk2 < 4; ++kk2) {
      const int idx = (ks * 4 + kk2) * 512 + lane * 8;
      bf16x8 h0 = *reinterpret_cast<const bf16x8*>(&c0[idx]);
      bf16x8 h1 = *reinterpret_cast<const bf16x8*>(&c1[idx]);
      bf16x8 h2 = *reinterpret_cast<const bf16x8*>(&c2[idx]);
      a1a = __builtin_amdgcn_mfma_f32_16x16x32_bf16(h0, w1c[0][kk2], a1a, 0, 0, 0);
      a1b = __builtin_amdgcn_mfma_f32_16x16x32_bf16(h1, w1c[0][kk2], a1b, 0, 0, 0);
      a1a = __builtin_amdgcn_mfma_f32_16x16x32_bf16(h0, w1c[1][kk2], a1a, 0, 0, 0);
      a1b = __builtin_amdgcn_mfma_f32_16x16x32_bf16(h2, w1c[0][kk2], a1b, 0, 0, 0);
      a1a = __builtin_amdgcn_mfma_f32_16x16x32_bf16(h1, w1c[1][kk2], a1a, 0, 0, 0);
      a1b = __builtin_amdgcn_mfma_f32_16x16x32_bf16(h0, w1c[2][kk2], a1b, 0, 0, 0);
    }
    if (!owner) {
      #pragma unroll
      for (int i = 0; i < 4; ++i)
        pbuf[(ks - 1) * 1024 + pb + i] = a1a[i] + a1b[i];
    }
    __syncthreads();
    float htv[4];
    if (owner) {
      #pragma unroll
      for (int i = 0; i < 4; ++i) {
        float pre = a1a[i] + a1b[i] + pbuf[pb + i] + pbuf[1024 + pb + i]
                  + pbuf[2048 + pb + i] + xv1v[i];
        float ht = tanhf(pre);
        float hn = zz[i] * (hreg[i] - ht) + ht;
        htv[i] = ht;
        hreg[i] = hn;
        st32_agent(&hx_g[fragbase + i * 8], hn);
      }
    }
    ++bar; group_barrier(flags_g, cw, bar, dead);
    if (owner) {
      #pragma unroll
      for (int i = 0; i < 4; ++i) {
        ht_h[rowb + (size_t)i * 512] = (__bf16)htv[i];
        h_h[rowb + (size_t)i * 512]  = (__bf16)hreg[i];
      }
      #pragma unroll
      for (int i = 0; i < 4; ++i) { xv1v[i] = xn1[i]; xv2v[i] = xn2[i]; xv3v[i] = xn3[i]; }
    }
    stage(hx_g);
    __syncthreads();
  }
  if (owner) {
    #pragma unroll
    for (int i = 0; i < 4; ++i) {
      int b = g * 16 + q * 4 + i;
      dout[O_HT + (size_t)b * 512 + colc] = hreg[i];
    }
  }
}

// =========================== K3a: logits/softmax/error ===========================
__global__ void k3a_soft(const float* __restrict__ Woutw, const float* __restrict__ Woutb,
                         const int* __restrict__ y, float* __restrict__ dout,
                         float* __restrict__ errw)
{
  const int b = blockIdx.x, o = threadIdx.x;
  const float* hrow = dout + O_HT + (size_t)b * 512;
  float sv = Woutb[o];
  for (int k = 0; k < 512; ++k) sv += hrow[k] * Woutw[(size_t)o * 512 + k];
  float mx = sv;
  for (int off = 32; off; off >>= 1) mx = fmaxf(mx, __shfl_xor(mx, off, 64));
  float e = expf(sv - mx);
  float sum = e;
  for (int off = 32; off; off >>= 1) sum += __shfl_xor(sum, off, 64);
  float outp = e / sum;
  float errv = outp - ((y[b] == o) ? 1.f : 0.f);
  dout[O_OUT + b * 64 + o] = outp;
  dout[O_ERR + b * 64 + o] = errv;
  errw[b * 64 + o] = errv;
}

// =========================== K3b: 6 DFA projections ===========================
__global__ __launch_bounds__(256)
void k3b_proj(const float* __restrict__ err,
              const float* b0, const float* b1, const float* b2,
              const float* b3, const float* b4, const float* b5,
              float* __restrict__ proj)
{
  const int p = blockIdx.y;
  const int hb = blockIdx.x * 64;
  const float* BX = (p==0)?b0:(p==1)?b1:(p==2)?b2:(p==3)?b3:(p==4)?b4:b5;
  __shared__ float es[64 * 64];
  __shared__ float bs[64 * 65];
  for (int i = threadIdx.x; i < 4096; i += 256) es[i] = err[i];
  for (int i = threadIdx.x; i < 4096; i += 256) {
    int o = i >> 6, hh = i & 63;
    bs[o * 65 + hh] = BX[(size_t)o * 512 + hb + hh];
  }
  __syncthreads();
  for (int e = 0; e < 16; ++e) {
    int idx = threadIdx.x + e * 256;
    int b = idx >> 6, hh = idx & 63;
    float s = 0.f;
    for (int o = 0; o < 64; ++o) s += es[b * 64 + o] * bs[o * 65 + hh];
    proj[(size_t)p * 32768 + b * 512 + hb + hh] = s;
  }
}

// =========================== E1T: HpT / RsHpT m-major [512][TB] ===========================
__global__ __launch_bounds__(256)
void e1t(const __bf16* __restrict__ r_h, const __bf16* __restrict__ h_h,
         __bf16* __restrict__ HpT, __bf16* __restrict__ RsHpT)
{
  const int t = blockIdx.y, hb = blockIdx.x * 64;
  const int tid = threadIdx.x;
  __shared__ __bf16 tr[64 * 68];
  float hpv[16], rv[16];
  #pragma unroll
  for (int e = 0; e < 16; ++e) {
    int idx = tid + e * 256;
    int b = idx >> 6, hl = idx & 63;
    hpv[e] = hprev_at(h_h, t * 64 + b, hb + hl);
    rv[e]  = (float)r_h[((size_t)t * 64 + b) * 512 + hb + hl];
  }
  for (int rnd = 0; rnd < 2; ++rnd) {
    __syncthreads();
    #pragma unroll
    for (int e = 0; e < 16; ++e) {
      int idx = tid + e * 256;
      int b = idx >> 6, hl = idx & 63;
      tr[b * 68 + hl] = (__bf16)(rnd == 0 ? hpv[e] : rv[e] * hpv[e]);
    }
    __syncthreads();
    __bf16* dst = (rnd == 0) ? HpT : RsHpT;
    #pragma unroll
    for (int e = 0; e < 16; ++e) {
      int idx = tid + e * 256;
      int hl2 = idx >> 6, b2 = idx & 63;
      dst[(size_t)(hb + hl2) * TBc + t * 64 + b2] = tr[b2 * 68 + hl2];
    }
  }
}

// =========================== K4: P = (G @ W1^T) * mul, G fused, m-major out ==========
__global__ __launch_bounds__(256)
void k4_pgemm(const __bf16* __restrict__ z_h, const __bf16* __restrict__ ht_h,
              const __bf16* __restrict__ r_h, const __bf16* __restrict__ h_h,
              const float* __restrict__ proj, const __bf16* __restrict__ W1b,
              __bf16* __restrict__ P)
{
  const int p = blockIdx.z;
  const int krow0 = blockIdx.x * 128;
  const int n0 = blockIdx.y * 128;
  const int pidx = (p == 0) ? 5 : (p == 1) ? 4 : (p == 2) ? 1 : 0;
  const float* pr = proj + (size_t)pidx * 32768;
  const int tid = threadIdx.x, lane = tid & 63, wv = tid >> 6, q = lane >> 4;
  const int wm = (wv & 1) * 64, wn = (wv >> 1) * 64;
  __shared__ __align__(16) __bf16 Al[128 * 40];
  __shared__ __align__(16) __bf16 Bl[128 * 40];
  f32x4 acc[4][4] = {};
  for (int kt = 0; kt < 16; ++kt) {
    const int h0 = kt * 32;
    __syncthreads();
    #pragma unroll
    for (int e = 0; e < 4; ++e) {
      int idx = tid + e * 256;                 // 0..1023
      int row = idx >> 3, h4 = (idx & 7) * 4;
      int kg = krow0 + row;
      bf16x4 zz = *reinterpret_cast<const bf16x4*>(&z_h[(size_t)kg * 512 + h0 + h4]);
      bf16x4 tt = *reinterpret_cast<const bf16x4*>(&ht_h[(size_t)kg * 512 + h0 + h4]);
      float4 pv = *reinterpret_cast<const float4*>(&pr[(size_t)(kg & 63) * 512 + h0 + h4]);
      float pvv[4] = {pv.x, pv.y, pv.z, pv.w};
      bf16x4 gv;
      #pragma unroll
      for (int j = 0; j < 4; ++j) {
        float sz = 1.f - (float)zz[j];
        float v = pvv[j] * sz;
        if (p < 2) { float h = (float)tt[j]; v *= (1.f - h * h); }
        gv[j] = (__bf16)v;
      }
      *reinterpret_cast<bf16x4*>(&Al[row * 40 + h4]) = gv;
      bf16x4 wv4 = *reinterpret_cast<const bf16x4*>(&W1b[(size_t)(n0 + row) * 512 + h0 + h4]);
      *reinterpret_cast<bf16x4*>(&Bl[row * 40 + h4]) = wv4;
    }
    __syncthreads();
    bf16x8 af[4], bfv[4];
    #pragma unroll
    for (int mi = 0; mi < 4; ++mi)
      af[mi] = *reinterpret_cast<const bf16x8*>(&Al[(wm + mi * 16 + (lane & 15)) * 40 + q * 8]);
    #pragma unroll
    for (int ni = 0; ni < 4; ++ni)
      bfv[ni] = *reinterpret_cast<const bf16x8*>(&Bl[(wn + ni * 16 + (lane & 15)) * 40 + q * 8]);
    #pragma unroll
    for (int mi = 0; mi < 4; ++mi)
      #pragma unroll
      for (int ni = 0; ni < 4; ++ni)
        acc[mi][ni] = __builtin_amdgcn_mfma_f32_16x16x32_bf16(af[mi], bfv[ni], acc[mi][ni], 0, 0, 0);
  }
  __bf16* Pp = P + (size_t)p * THW;
  #pragma unroll
  for (int mi = 0; mi < 4; ++mi) {
    const int kg = krow0 + wm + mi * 16 + q * 4;
    const int tt = kg >> 6;
    #pragma unroll
    for (int ni = 0; ni < 4; ++ni) {
      const int n = n0 + wn + ni * 16 + (lane & 15);
      union { __bf16 b[4]; uint2 u; } pk;
      #pragma unroll
      for (int i = 0; i < 4; ++i) {
        float mul;
        if (p < 2) {
          float r = (float)r_h[(size_t)(kg + i) * 512 + n];
          float hp = 0.f;
          if (tt != 1) {
            int kr = (tt == 0) ? (16320 + (kg & 63) + i) : (kg + i - 128);
            hp = (float)h_h[(size_t)kr * 512 + n];
          }
          mul = hp * r * (1.f - r);
        } else {
          float h = (float)ht_h[(size_t)(kg + i) * 512 + n];
          mul = 1.f - h * h;
        }
        pk.b[i] = (__bf16)(acc[mi][ni][i] * mul);
      }
      *reinterpret_cast<uint2*>(&Pp[(size_t)n * TBc + kg]) = pk.u;
    }
  }
}

// =========================== K5: TN grad GEMM, split-k atomics into d_out ==========
__global__ __launch_bounds__(256)
void k5_grad(const __bf16* __restrict__ Ap, int amode, const __bf16* __restrict__ Bp,
             const __bf16* __restrict__ r_h, const __bf16* __restrict__ ht_h,
             const __bf16* __restrict__ h_h, const float* __restrict__ projA,
             float* __restrict__ out, int N, int klen, float scale)
{
  const int m0 = blockIdx.x * 128;
  const int n0 = blockIdx.y * 128;
  const int tid = threadIdx.x, lane = tid & 63, wv = tid >> 6, q = lane >> 4;
  const int wm = (wv & 1) * 64, wn = (wv >> 1) * 64;
  __shared__ __align__(16) __bf16 Al[128 * 72];
  __shared__ __align__(16) __bf16 Bl[128 * 72];
  f32x4 acc[4][4] = {};
  const int iters = klen >> 6;
  for (int kt = 0; kt < iters; ++kt) {
    const int kk0 = blockIdx.z * klen + kt * 64;
    __syncthreads();
    #pragma unroll
    for (int e = 0; e < 8; ++e) {
      int idx = tid + e * 256;              // 0..2047
      int row = idx >> 4, c4 = (idx & 15) * 4;
      bf16x4 bv = *reinterpret_cast<const bf16x4*>(&Bp[(size_t)(n0 + row) * TBc + kk0 + c4]);
      *reinterpret_cast<bf16x4*>(&Bl[row * 72 + c4]) = bv;
    }
    if (amode == 0) {
      #pragma unroll
      for (int e = 0; e < 8; ++e) {
        int idx = tid + e * 256;
        int row = idx >> 4, c4 = (idx & 15) * 4;
        bf16x4 av = *reinterpret_cast<const bf16x4*>(&Ap[(size_t)(m0 + row) * TBc + kk0 + c4]);
        *reinterpret_cast<bf16x4*>(&Al[row * 72 + c4]) = av;
      }
    } else {
      #pragma unroll
      for (int e = 0; e < 8; ++e) {
        int idx = tid + e * 256;
        int kk = idx >> 5;                  // 0..63 local k row
        int m4 = (idx & 31) * 4;
        int kg = kk0 + kk;
        int tt = kg >> 6;
        bf16x4 hs = *reinterpret_cast<const bf16x4*>(&ht_h[(size_t)kg * 512 + m0 + m4]);
        bf16x4 rv = *reinterpret_cast<const bf16x4*>(&r_h[(size_t)kg * 512 + m0 + m4]);
        float4 pv = *reinterpret_cast<const float4*>(&projA[(size_t)(kg & 63) * 512 + m0 + m4]);
        float pvv[4] = {pv.x, pv.y, pv.z, pv.w};
        float hpf[4] = {0.f, 0.f, 0.f, 0.f};
        if (tt != 1) {
          int kr = (tt == 0) ? (16320 + (kg & 63)) : (kg - 128);
          bf16x4 hp = *reinterpret_cast<const bf16x4*>(&h_h[(size_t)kr * 512 + m0 + m4]);
          #pragma unroll
          for (int j = 0; j < 4; ++j) hpf[j] = (float)hp[j];
        }
        #pragma unroll
        for (int j = 0; j < 4; ++j) {
          float r = (float)rv[j];
          float zg = (hpf[j] - (float)hs[j]) * r * (1.f - r) * pvv[j];
          Al[(m4 + j) * 72 + kk] = (__bf16)zg;
        }
      }
    }
    __syncthreads();
    #pragma unroll
    for (int ks = 0; ks < 2; ++ks) {
      bf16x8 af[4], bfv[4];
      #pragma unroll
      for (int mi = 0; mi < 4; ++mi)
        af[mi] = *reinterpret_cast<const bf16x8*>(&Al[(wm + mi * 16 + (lane & 15)) * 72 + ks * 32 + q * 8]);
      #pragma unroll
      for (int ni = 0; ni < 4; ++ni)
        bfv[ni] = *reinterpret_cast<const bf16x8*>(&Bl[(wn + ni * 16 + (lane & 15)) * 72 + ks * 32 + q * 8]);
      #pragma unroll
      for (int mi = 0; mi < 4; ++mi)
        #pragma unroll
        for (int ni = 0; ni < 4; ++ni)
          acc[mi][ni] = __builtin_amdgcn_mfma_f32_16x16x32_bf16(af[mi], bfv[ni], acc[mi][ni], 0, 0, 0);
    }
  }
  #pragma unroll
  for (int mi = 0; mi < 4; ++mi) {
    const int m = m0 + wm + mi * 16 + q * 4;
    #pragma unroll
    for (int ni = 0; ni < 4; ++ni) {
      const int n = n0 + wn + ni * 16 + (lane & 15);
      #pragma unroll
      for (int i = 0; i < 4; ++i)
        atomicAdd(&out[(size_t)(m + i) * N + n], acc[mi][ni][i] * scale);
    }
  }
}

// =========================== db kernels ===========================
__global__ void k_dbP(const __bf16* __restrict__ P, float* __restrict__ db)
{
  const __bf16* row = P + (size_t)blockIdx.x * TBc;
  float sv = 0.f;
  for (int i = threadIdx.x; i < TBc; i += 256) sv += (float)row[i];
  for (int off = 32; off; off >>= 1) sv += __shfl_xor(sv, off, 64);
  __shared__ float red[4];
  if ((threadIdx.x & 63) == 0) red[threadIdx.x >> 6] = sv;
  __syncthreads();
  if (threadIdx.x == 0)
    atomicAdd(&db[blockIdx.x], (red[0] + red[1] + red[2] + red[3]) * (1.f / 64.f));
}

__global__ void k_dbzg(const __bf16* __restrict__ r_h, const __bf16* __restrict__ ht_h,
                       const __bf16* __restrict__ h_h, const float* __restrict__ proj,
                       float* __restrict__ db)
{
  const int hb = blockIdx.x * 64;
  const int col = hb + (threadIdx.x & 63);
  const int part = threadIdx.x >> 6;
  const int kb = blockIdx.y * 1024;
  float sum = 0.f;
  for (int k = kb + part; k < kb + 1024; k += 4) {
    float hs = (float)ht_h[(size_t)k * 512 + col];
    float r  = (float)r_h[(size_t)k * 512 + col];
    float hp = hprev_at(h_h, k, col);
    float pv = proj[3 * 32768 + (size_t)(k & 63) * 512 + col];
    sum += (hp - hs) * r * (1.f - r) * pv;
  }
  __shared__ float sred[4][64];
  sred[part][threadIdx.x & 63] = sum;
  __syncthreads();
  if (threadIdx.x < 64)
    atomicAdd(&db[512 + hb + threadIdx.x],
              (sred[0][threadIdx.x] + sred[1][threadIdx.x] +
               sred[2][threadIdx.x] + sred[3][threadIdx.x]) * (1.f / 64.f));
}

// =========================== K6: norm + clip (grads live in d_out) ===========================
__global__ void k6a_sumsq(const float* __restrict__ dout, const float* __restrict__ db,
                          float* __restrict__ slots)
{
  const int yy = blockIdx.y;
  const float* src; int count;
  if (yy < 3)      { src = dout + O_DW0 + (size_t)yy * 262144; count = 262144; }
  else if (yy < 6) { src = dout + O_DV0 + (size_t)(yy - 3) * 65536; count = 65536; }
  else             { src = db + (size_t)(yy - 6) * 512; count = 512; }
  int start = blockIdx.x * 4096;
  if (start >= count) return;
  int end = min(start + 4096, count);
  float sp = 0.f;
  for (int i = start + threadIdx.x; i < end; i += 256) { float v = src[i]; sp += v * v; }
  for (int off = 32; off; off >>= 1) sp += __shfl_xor(sp, off, 64);
  __shared__ float red[4];
  if ((threadIdx.x & 63) == 0) red[threadIdx.x >> 6] = sp;
  __syncthreads();
  if (threadIdx.x == 0) atomicAdd(&slots[yy], red[0] + red[1] + red[2] + red[3]);
}

__global__ void k6b_write(const float* __restrict__ db,
                          const float* __restrict__ slots, float* __restrict__ dout)
{
  const int yy = blockIdx.y;
  const float* src; int count; size_t oo;
  if (yy < 3)      { oo = O_DW0 + (size_t)yy * 262144; src = dout + oo; count = 262144; }
  else if (yy < 6) { oo = O_DV0 + (size_t)(yy - 3) * 65536; src = dout + oo; count = 65536; }
  else             { oo = O_DB0 + (size_t)(yy - 6) * 512; src = db + (size_t)(yy - 6) * 512; count = 512; }
  int start = blockIdx.x * 4096;
  if (start >= count) return;
  int end = min(start + 4096, count);
  float inv = 1.f / sqrtf(slots[yy]);
  for (int i = start + threadIdx.x; i < end; i += 256) {
    float v = src[i] * inv;
    dout[oo + i] = fminf(fmaxf(v, -5.f), 5.f);
  }
}

// =========================== launch ===========================
extern "C" void kernel_launch(void* const* d_in, const int* in_sizes, int n_in,
                              void* d_out, int out_size, void* d_ws, size_t ws_size,
                              hipStream_t stream)
{
  const float* x     = (const float*)d_in[0];
  const int*   y     = (const int*)d_in[1];
  const float* W1w   = (const float*)d_in[2];
  const float* V1w   = (const float*)d_in[3];
  const float* V1b   = (const float*)d_in[4];
  const float* W2w   = (const float*)d_in[5];
  const float* W2b   = (const float*)d_in[6];
  const float* V2w   = (const float*)d_in[7];
  const float* W3w   = (const float*)d_in[8];
  const float* W3b   = (const float*)d_in[9];
  const float* V3w   = (const float*)d_in[10];
  const float* Woutw = (const float*)d_in[11];
  const float* Woutb = (const float*)d_in[12];
  const float* BW1   = (const float*)d_in[13];
  const float* BV1   = (const float*)d_in[14];
  const float* BW2   = (const float*)d_in[15];
  const float* BV2   = (const float*)d_in[16];
  const float* BW3   = (const float*)d_in[17];
  const float* BV3   = (const float*)d_in[18];
  float* dout = (float*)d_out;
  char* ws = (char*)d_ws;

  if (ws_size < W_NEED) { ksent<<<1, 1, 0, stream>>>(dout, (float)ws_size); return; }

  float*  slots = (float*)(ws + W_SLOT);
  float*  dbr   = (float*)(ws + W_DB);
  int*    flg   = (int*)(ws + W_FLG);
  float*  errw  = (float*)(ws + W_ERRW);
  float*  proj  = (float*)(ws + W_PROJ);
  __bf16* W1b   = (__bf16*)(ws + W_W1B);
  float*  hx    = (float*)(ws + W_HX);
  float*  hrx   = (float*)(ws + W_HRX);
  __bf16* XT    = (__bf16*)(ws + W_XT);
  __bf16* r_h   = (__bf16*)(ws + W_HIST);
  __bf16* z_h   = (__bf16*)(ws + W_HIST + 16777216);
  __bf16* ht_h  = (__bf16*)(ws + W_HIST + 33554432);
  __bf16* h_h   = (__bf16*)(ws + W_HIST + 50331648);
  char*   PB    = ws + W_PB;

  // xV fp32 (dead after k2) aliases P/HpT/RsHpT (live after k2)
  float* xv1 = (float*)PB;
  float* xv2 = (float*)(PB + 33554432);
  float* xv3 = (float*)(PB + 67108864);
  __bf16* P     = (__bf16*)PB;                     // 4 x [512][TB] bf16 = 67.1 MB
  __bf16* HpT   = (__bf16*)(PB + 67108864);
  __bf16* RsHpT = (__bf16*)(PB + 83886080);

  kzero<<<16, 256, 0, stream>>>((float*)ws, 4096);                  // ctr+slots+dbr+flags
  kzero<<<3840, 256, 0, stream>>>(dout + O_DW0, 983040);            // grad accumulators
  k0_cast<<<1024, 256, 0, stream>>>(W1w, W1b, 262144);
  k1_xv<<<dim3(24, 256), 256, 0, stream>>>(x, V1w, V2w, V3w, V1b, W2b, W3b, xv1, xv2, xv3);
  e0_xt<<<256, 256, 0, stream>>>(x, XT);
  k2_recur<<<64, 512, 0, stream>>>(W1w, W2w, W3w, xv1, xv2, xv3,
                                   r_h, z_h, ht_h, h_h, hx, hrx, flg, dout);
  k3a_soft<<<64, 64, 0, stream>>>(Woutw, Woutb, y, dout, errw);
  k3b_proj<<<dim3(8, 6), 256, 0, stream>>>(errw, BW1, BV1, BW2, BV2, BW3, BV3, proj);
  e1t<<<dim3(8, 256), 256, 0, stream>>>(r_h, h_h, HpT, RsHpT);
  k_dbzg<<<dim3(8, 16), 256, 0, stream>>>(r_h, ht_h, h_h, proj, dbr);   // db1

  k4_pgemm<<<dim3(128, 4, 4), 256, 0, stream>>>(z_h, ht_h, r_h, h_h, proj, W1b, P);
  const float sc = 1.f / 64.f;
  // dW0 = HW^T @ RsHp ; dW1 = zgW^T @ Hp ; dW2 = AW^T @ Hp
  k5_grad<<<dim3(4, 4, 16), 256, 0, stream>>>(P + 3 * THW, 0, RsHpT, r_h, ht_h, h_h, proj,
                                              dout + O_DW0, 512, 1024, sc);
  k5_grad<<<dim3(4, 4, 16), 256, 0, stream>>>(nullptr, 1, HpT, r_h, ht_h, h_h, proj + 2 * 32768,
                                              dout + O_DW0 + 262144, 512, 1024, sc);
  k5_grad<<<dim3(4, 4, 16), 256, 0, stream>>>(P + 1 * THW, 0, HpT, r_h, ht_h, h_h, proj,
                                              dout + O_DW0 + 524288, 512, 1024, sc);
  // dV0 = HV^T @ X ; dV1 = zgV^T @ X ; dV2 = AV^T @ X
  k5_grad<<<dim3(4, 1, 16), 256, 0, stream>>>(P + 2 * THW, 0, XT, r_h, ht_h, h_h, proj,
                                              dout + O_DV0, 128, 1024, sc);
  k5_grad<<<dim3(4, 1, 16), 256, 0, stream>>>(nullptr, 1, XT, r_h, ht_h, h_h, proj + 3 * 32768,
                                              dout + O_DV0 + 65536, 128, 1024, sc);
  k5_grad<<<dim3(4, 1, 16), 256, 0, stream>>>(P + 0 * THW, 0, XT, r_h, ht_h, h_h, proj,
                                              dout + O_DV0 + 131072, 128, 1024, sc);
  k_dbP<<<512, 256, 0, stream>>>(P + 2 * THW, dbr);            // db0 from HV
  k_dbP<<<512, 256, 0, stream>>>(P + 0 * THW, dbr + 1024);     // db2 from AV
  k6a_sumsq<<<dim3(64, 9), 256, 0, stream>>>(dout, dbr, slots);
  k6b_write<<<dim3(64, 9), 256, 0, stream>>>(dbr, slots, dout);
}

// Round 3
// 2704.622 us; speedup vs baseline: 1.1703x; 1.1703x over previous
//
#include <hip/hip_runtime.h>
#include <hip/hip_bf16.h>

#define DI __device__ __forceinline__

typedef __bf16 bf16x8 __attribute__((ext_vector_type(8)));
typedef __bf16 bf16x4 __attribute__((ext_vector_type(4)));
typedef __bf16 bf16x2 __attribute__((ext_vector_type(2)));
typedef float  f32x4  __attribute__((ext_vector_type(4)));
typedef unsigned long long ull;

static constexpr int Bc = 64, Tc = 256, Ic = 128, Hc = 512, Oc = 64;
static constexpr int TBc = Tc * Bc;                 // 16384
static constexpr size_t THW = (size_t)TBc * Hc;     // 8388608 elems

// ---------- d_out offsets (floats) ----------
static constexpr size_t O_OUT = 0;
static constexpr size_t O_HT  = 4096;
static constexpr size_t O_DW0 = 36864;
static constexpr size_t O_DV0 = 823296;
static constexpr size_t O_DB0 = 1019904;
static constexpr size_t O_ERR = 1021440;

// ---------- ws offsets (bytes) ----------
static constexpr size_t W_CTR  = 0;        // legacy counter region (unused)
static constexpr size_t W_SLOT = 1024;     // 9 f32
static constexpr size_t W_DB   = 2048;     // db_raw [3][512] f32 -> ends 8192
static constexpr size_t W_FLG  = 8192;     // barrier epoch flags: 64 slots x 128B -> ends 16384
static constexpr size_t W_ERRW = 16384;    // error [64][64] f32
static constexpr size_t W_PROJ = 32768;    // proj [6][64][512] f32 -> ends 819200
static constexpr size_t W_W1B  = 819200;   // W1 bf16 [512][512] -> ends 1343488
static constexpr size_t W_HX   = 1343488;  // h exchange fp32 [4][8192] (128 KB)
static constexpr size_t W_HRX  = 1474560;  // hr exchange fp32 [4][8192] -> ends 1605632
static constexpr size_t W_XT   = 1605632;  // x^T bf16 [128][TB] -> ends 5799936
static constexpr size_t W_HIST = 5799936;  // r,z,ht,h bf16 [TB][512] each -> ends 72908800
static constexpr size_t W_PB   = 72908800; // xV fp32 (100.6MB) / later P + HpT + RsHpT
static constexpr size_t W_NEED = W_PB + 100663296;   // 173572096

// =========================== helpers ===========================

DI void st32_agent(float* p, float v) {
  __hip_atomic_store((unsigned int*)p, __float_as_uint(v),
                     __ATOMIC_RELAXED, __HIP_MEMORY_SCOPE_AGENT);
}
DI ull ld64_agent(const void* p) {
  return __hip_atomic_load((ull*)p, __ATOMIC_RELAXED, __HIP_MEMORY_SCOPE_AGENT);
}

// Fence-free group barrier via distributed epoch flags. Each wg STORES the
// epoch to its own 128B-strided slot (no RMW); wave 0 polls all 16 slots with
// 16 parallel lanes. The leading __syncthreads() emits s_waitcnt vmcnt(0) per
// wave, draining the agent-scope exchange stores before the flag store.
DI void group_barrier(int* flags_g, int myslot, int bar, bool& dead) {
  __syncthreads();
  if (threadIdx.x == 0)
    __hip_atomic_store(&flags_g[myslot * 32], bar,
                       __ATOMIC_RELAXED, __HIP_MEMORY_SCOPE_AGENT);
  if (threadIdx.x < 64 && !dead) {
    const int l = threadIdx.x;
    int spins = 0;
    for (;;) {
      int v = bar;
      if (l < 16)
        v = __hip_atomic_load(&flags_g[l * 32],
                              __ATOMIC_RELAXED, __HIP_MEMORY_SCOPE_AGENT);
      if (__all(v >= bar)) break;
      __builtin_amdgcn_s_sleep(1);
      if (++spins > 4000000) { dead = true; break; }   // never hang the bench
    }
  }
  __syncthreads();
}

// hiddens[t-1] with python-negative-index quirk; k = t*64+b
DI float hprev_at(const __bf16* __restrict__ h_h, int k, int col) {
  int t = k >> 6;
  if (t == 1) return 0.f;
  int row = (t == 0) ? (16320 + (k & 63)) : (k - 128);
  return (float)h_h[(size_t)row * 512 + col];
}

// =========================== tiny kernels ===========================

__global__ void kzero(float* __restrict__ p, int n) {
  int i = blockIdx.x * 256 + threadIdx.x;
  if (i < n) p[i] = 0.f;
}
__global__ void ksent(float* p, float v) { p[0] = v; }
__global__ void k0_cast(const float* __restrict__ s, __bf16* __restrict__ d, int n) {
  int i = blockIdx.x * 256 + threadIdx.x;
  if (i < n) d[i] = (__bf16)s[i];
}

// =========================== K1: xV = x@V^T + bias (fp32) ===========================
__global__ __launch_bounds__(256)
void k1_xv(const float* __restrict__ x, const float* __restrict__ V1w,
           const float* __restrict__ V2w, const float* __restrict__ V3w,
           const float* __restrict__ V1b, const float* __restrict__ W2b,
           const float* __restrict__ W3b,
           float* __restrict__ xv1f, float* __restrict__ xv2f, float* __restrict__ xv3f)
{
  const int cb = blockIdx.x, t = blockIdx.y;
  const int g = cb >> 3, jblk = cb & 7;
  const float* Vg   = (g == 0) ? V1w : (g == 1) ? V2w : V3w;
  const float* bias = (g == 0) ? V1b : (g == 1) ? W2b : W3b;
  float* of = (g == 0) ? xv1f : (g == 1) ? xv2f : xv3f;
  __shared__ float As[64 * 69];
  __shared__ float Bs[64 * 69];
  const int tid = threadIdx.x;
  float acc[4][4] = {};
  const int m0 = (tid & 15) * 4, j0 = (tid >> 4) * 4;
  for (int kc = 0; kc < 2; ++kc) {
    __syncthreads();
    #pragma unroll
    for (int e = 0; e < 4; ++e) {
      int idx = tid + e * 256;            // 0..1023
      int row = idx >> 4, c4 = (idx & 15) * 4;
      float4 v = *reinterpret_cast<const float4*>(&x[((size_t)row * 256 + t) * 128 + kc * 64 + c4]);
      As[row * 69 + c4 + 0] = v.x; As[row * 69 + c4 + 1] = v.y;
      As[row * 69 + c4 + 2] = v.z; As[row * 69 + c4 + 3] = v.w;
      float4 w = *reinterpret_cast<const float4*>(&Vg[(size_t)(jblk * 64 + row) * 128 + kc * 64 + c4]);
      Bs[row * 69 + c4 + 0] = w.x; Bs[row * 69 + c4 + 1] = w.y;
      Bs[row * 69 + c4 + 2] = w.z; Bs[row * 69 + c4 + 3] = w.w;
    }
    __syncthreads();
    for (int i = 0; i < 64; ++i) {
      float a[4], b[4];
      #pragma unroll
      for (int u = 0; u < 4; ++u) a[u] = As[(m0 + u) * 69 + i];
      #pragma unroll
      for (int u = 0; u < 4; ++u) b[u] = Bs[(j0 + u) * 69 + i];
      #pragma unroll
      for (int mi = 0; mi < 4; ++mi)
        #pragma unroll
        for (int ji = 0; ji < 4; ++ji) acc[mi][ji] += a[mi] * b[ji];
    }
  }
  #pragma unroll
  for (int ji = 0; ji < 4; ++ji) {
    int jg = jblk * 64 + j0 + ji;
    float bv = bias[jg];
    #pragma unroll
    for (int mi = 0; mi < 4; ++mi) {
      int b = m0 + mi;
      of[((size_t)t * 64 + b) * 512 + jg] = acc[mi][ji] + bv;
    }
  }
}

// =========================== E0: X^T bf16 [128][TB] ===========================
__global__ void e0_xt(const float* __restrict__ x, __bf16* __restrict__ XT)
{
  const int t = blockIdx.x;
  __shared__ __bf16 xs[64 * 132];
  const int tid = threadIdx.x;
  #pragma unroll
  for (int e = 0; e < 8; ++e) {
    int idx = tid + e * 256;              // 0..2047
    int b = idx >> 5, c4 = (idx & 31) * 4;
    float4 v = *reinterpret_cast<const float4*>(&x[((size_t)b * 256 + t) * 128 + c4]);
    xs[b * 132 + c4 + 0] = (__bf16)v.x; xs[b * 132 + c4 + 1] = (__bf16)v.y;
    xs[b * 132 + c4 + 2] = (__bf16)v.z; xs[b * 132 + c4 + 3] = (__bf16)v.w;
  }
  __syncthreads();
  #pragma unroll
  for (int e = 0; e < 8; ++e) {
    int idx = tid + e * 256;
    int i = idx >> 4, b4 = (idx & 15) * 4;
    __bf16* d = &XT[(size_t)i * TBc + t * 64 + b4];
    d[0] = xs[(b4 + 0) * 132 + i];
    d[1] = xs[(b4 + 1) * 132 + i];
    d[2] = xs[(b4 + 2) * 132 + i];
    d[3] = xs[(b4 + 3) * 132 + i];
  }
}

// =========================== K2: persistent GRU recurrence, fp32-faithful =========
// 64 wgs = 4 batch-groups(16 rows) x 16 col-wgs(32 cols). 4 waves/wg =
// 2 col-tiles x 2 k-halves (8 kk each). Both operands split 3-way bf16
// (24-bit mantissa, Ootomo 6-term MFMA, residual ~2^-24). h exchanged fp32.
// Exchange layout == LDS fragment layout (identity), so consumer reload is
// lane-consecutive 8B loads (coalesced 512B/wave-instr) with conflict-free
// 4B-stride ds_writes. pbuf lane stride = 9 floats (coprime with 32 banks;
// stride 8 was an 8-way conflict -- R1's residual 6.3e6 SQ_LDS_BANK_CONFLICT).
__global__ __launch_bounds__(256, 1)
void k2_recur(const float* __restrict__ W1w, const float* __restrict__ W2w,
              const float* __restrict__ W3w,
              const float* __restrict__ xv1, const float* __restrict__ xv2,
              const float* __restrict__ xv3,
              __bf16* __restrict__ r_h, __bf16* __restrict__ z_h,
              __bf16* __restrict__ ht_h, __bf16* __restrict__ h_h,
              float* __restrict__ hx, float* __restrict__ hrx,
              int* __restrict__ flags, float* __restrict__ dout)
{
  const int g  = blockIdx.x >> 4;      // batch group 0..3
  const int cw = blockIdx.x & 15;      // col-wg 0..15
  const int tid = threadIdx.x, lane = tid & 63, wv = tid >> 6;
  const int kh = wv & 1;               // k-half
  const int ct = wv >> 1;              // col-tile
  const int q  = lane >> 4;
  const int colc = cw * 32 + ct * 16 + (lane & 15);
  const bool owner = (kh == 0);

  __shared__ __align__(16) __bf16 c0[8192];   // h comp0 frags [16kk][64lane][8]
  __shared__ __align__(16) __bf16 c1[8192];
  __shared__ __align__(16) __bf16 c2[8192];
  __shared__ float pbuf[128 * 9];             // cross-wave partials, 9-stride

  // weight fragments, 3-way split: lane n=colc, k = (kh*8+kk2)*32 + q*8 + j
  bf16x8 w1c[3][8], w2c[3][8], w3c[3][8];
  #pragma unroll
  for (int kk2 = 0; kk2 < 8; ++kk2) {
    const int kb = (kh * 8 + kk2) * 32 + q * 8;
    #pragma unroll
    for (int j = 0; j < 8; ++j) {
      float w = W1w[(size_t)colc * 512 + kb + j];
      __bf16 a = (__bf16)w; float r1 = w - (float)a;
      __bf16 b = (__bf16)r1;
      w1c[0][kk2][j] = a; w1c[1][kk2][j] = b; w1c[2][kk2][j] = (__bf16)(r1 - (float)b);
      w = W2w[(size_t)colc * 512 + kb + j];
      a = (__bf16)w; r1 = w - (float)a; b = (__bf16)r1;
      w2c[0][kk2][j] = a; w2c[1][kk2][j] = b; w2c[2][kk2][j] = (__bf16)(r1 - (float)b);
      w = W3w[(size_t)colc * 512 + kb + j];
      a = (__bf16)w; r1 = w - (float)a; b = (__bf16)r1;
      w3c[0][kk2][j] = a; w3c[1][kk2][j] = b; w3c[2][kk2][j] = (__bf16)(r1 - (float)b);
    }
  }
  for (int i = tid; i < 8192; i += 256) {
    c0[i] = (__bf16)0.f; c1[i] = (__bf16)0.f; c2[i] = (__bf16)0.f;
  }
  __syncthreads();

  float hreg[4] = {0.f, 0.f, 0.f, 0.f};
  float* hx_g  = hx  + g * 8192;
  float* hrx_g = hrx + g * 8192;
  int* flags_g = flags + g * 16 * 32;
  // frag index for state element (m=q*4+i, c=colc)
  const int fragbase = (colc >> 5) * 512 + (((colc >> 3) & 3) * 16 + q * 4) * 8 + (colc & 7);
  const int pb = (ct * 64 + lane) * 9;

  // coalesced exchange reload: lane-consecutive ull loads, identity map to
  // the c0/c1/c2 fragment layout (LDS byte offset = 4 * ull index).
  auto stage = [&](const float* __restrict__ srcf) {
    const ull* src = reinterpret_cast<const ull*>(srcf);
    ull u[16];
    #pragma unroll
    for (int j = 0; j < 16; ++j) u[j] = ld64_agent(src + j * 256 + tid);
    #pragma unroll
    for (int j = 0; j < 16; ++j) {
      float f0 = __uint_as_float((unsigned int)u[j]);
      float f1 = __uint_as_float((unsigned int)(u[j] >> 32));
      __bf16 a0 = (__bf16)f0; float r0 = f0 - (float)a0; __bf16 b0 = (__bf16)r0;
      __bf16 d0 = (__bf16)(r0 - (float)b0);
      __bf16 a1 = (__bf16)f1; float r1 = f1 - (float)a1; __bf16 b1 = (__bf16)r1;
      __bf16 d1 = (__bf16)(r1 - (float)b1);
      int o = (j * 256 + tid) * 2;
      bf16x2 v0; v0[0] = a0; v0[1] = a1;
      bf16x2 v1; v1[0] = b0; v1[1] = b1;
      bf16x2 v2; v2[0] = d0; v2[1] = d1;
      *reinterpret_cast<bf16x2*>(&c0[o]) = v0;
      *reinterpret_cast<bf16x2*>(&c1[o]) = v1;
      *reinterpret_cast<bf16x2*>(&c2[o]) = v2;
    }
  };

  bool dead = false;
  int bar = 0;
  #pragma unroll 1
  for (int t = 0; t < Tc; ++t) {
    const size_t rowb = ((size_t)t * 64 + g * 16 + q * 4) * 512 + colc;
    float xv1v[4], xv2v[4], xv3v[4];
    if (owner) {
      #pragma unroll
      for (int i = 0; i < 4; ++i) {
        size_t o = rowb + (size_t)i * 512;
        xv1v[i] = xv1[o]; xv2v[i] = xv2[o]; xv3v[i] = xv3[o];
      }
    }
    // ---- phase 1: z, r gates ----
    f32x4 a2 = {0.f,0.f,0.f,0.f}, a3 = {0.f,0.f,0.f,0.f};
    #pragma unroll
    for (int kk2 = 0; kk2 < 8; ++kk2) {
      const int idx = (kh * 8 + kk2) * 512 + lane * 8;
      bf16x8 h0 = *reinterpret_cast<const bf16x8*>(&c0[idx]);
      bf16x8 h1 = *reinterpret_cast<const bf16x8*>(&c1[idx]);
      bf16x8 h2 = *reinterpret_cast<const bf16x8*>(&c2[idx]);
      a2 = __builtin_amdgcn_mfma_f32_16x16x32_bf16(h0, w2c[0][kk2], a2, 0, 0, 0);
      a2 = __builtin_amdgcn_mfma_f32_16x16x32_bf16(h1, w2c[0][kk2], a2, 0, 0, 0);
      a2 = __builtin_amdgcn_mfma_f32_16x16x32_bf16(h0, w2c[1][kk2], a2, 0, 0, 0);
      a2 = __builtin_amdgcn_mfma_f32_16x16x32_bf16(h2, w2c[0][kk2], a2, 0, 0, 0);
      a2 = __builtin_amdgcn_mfma_f32_16x16x32_bf16(h1, w2c[1][kk2], a2, 0, 0, 0);
      a2 = __builtin_amdgcn_mfma_f32_16x16x32_bf16(h0, w2c[2][kk2], a2, 0, 0, 0);
      a3 = __builtin_amdgcn_mfma_f32_16x16x32_bf16(h0, w3c[0][kk2], a3, 0, 0, 0);
      a3 = __builtin_amdgcn_mfma_f32_16x16x32_bf16(h1, w3c[0][kk2], a3, 0, 0, 0);
      a3 = __builtin_amdgcn_mfma_f32_16x16x32_bf16(h0, w3c[1][kk2], a3, 0, 0, 0);
      a3 = __builtin_amdgcn_mfma_f32_16x16x32_bf16(h2, w3c[0][kk2], a3, 0, 0, 0);
      a3 = __builtin_amdgcn_mfma_f32_16x16x32_bf16(h1, w3c[1][kk2], a3, 0, 0, 0);
      a3 = __builtin_amdgcn_mfma_f32_16x16x32_bf16(h0, w3c[2][kk2], a3, 0, 0, 0);
    }
    if (!owner) {
      #pragma unroll
      for (int i = 0; i < 4; ++i) { pbuf[pb + i] = a2[i]; pbuf[pb + 4 + i] = a3[i]; }
    }
    __syncthreads();
    float zz[4], rr4[4];
    if (owner) {
      // exchange stores first (they gate the barrier), history stores after
      #pragma unroll
      for (int i = 0; i < 4; ++i) {
        float s2 = a2[i] + pbuf[pb + i]     + xv2v[i];
        float s3 = a3[i] + pbuf[pb + 4 + i] + xv3v[i];
        zz[i]  = 1.f / (1.f + expf(-s2));
        rr4[i] = 1.f / (1.f + expf(-s3));
        st32_agent(&hrx_g[fragbase + i * 8], hreg[i] * rr4[i]);
      }
      #pragma unroll
      for (int i = 0; i < 4; ++i) {
        z_h[rowb + (size_t)i * 512] = (__bf16)zz[i];
        r_h[rowb + (size_t)i * 512] = (__bf16)rr4[i];
      }
    }
    ++bar; group_barrier(flags_g, cw, bar, dead);
    stage(hrx_g);
    __syncthreads();
    // ---- phase 2: candidate + update ----
    f32x4 a1 = {0.f,0.f,0.f,0.f};
    #pragma unroll
    for (int kk2 = 0; kk2 < 8; ++kk2) {
      const int idx = (kh * 8 + kk2) * 512 + lane * 8;
      bf16x8 h0 = *reinterpret_cast<const bf16x8*>(&c0[idx]);
      bf16x8 h1 = *reinterpret_cast<const bf16x8*>(&c1[idx]);
      bf16x8 h2 = *reinterpret_cast<const bf16x8*>(&c2[idx]);
      a1 = __builtin_amdgcn_mfma_f32_16x16x32_bf16(h0, w1c[0][kk2], a1, 0, 0, 0);
      a1 = __builtin_amdgcn_mfma_f32_16x16x32_bf16(h1, w1c[0][kk2], a1, 0, 0, 0);
      a1 = __builtin_amdgcn_mfma_f32_16x16x32_bf16(h0, w1c[1][kk2], a1, 0, 0, 0);
      a1 = __builtin_amdgcn_mfma_f32_16x16x32_bf16(h2, w1c[0][kk2], a1, 0, 0, 0);
      a1 = __builtin_amdgcn_mfma_f32_16x16x32_bf16(h1, w1c[1][kk2], a1, 0, 0, 0);
      a1 = __builtin_amdgcn_mfma_f32_16x16x32_bf16(h0, w1c[2][kk2], a1, 0, 0, 0);
    }
    if (!owner) {
      #pragma unroll
      for (int i = 0; i < 4; ++i) pbuf[pb + i] = a1[i];
    }
    __syncthreads();
    if (owner) {
      float htv[4];
      #pragma unroll
      for (int i = 0; i < 4; ++i) {
        float pre = a1[i] + pbuf[pb + i] + xv1v[i];
        float ht = tanhf(pre);
        float hn = zz[i] * (hreg[i] - ht) + ht;
        htv[i] = ht;
        hreg[i] = hn;
        st32_agent(&hx_g[fragbase + i * 8], hn);
      }
      #pragma unroll
      for (int i = 0; i < 4; ++i) {
        ht_h[rowb + (size_t)i * 512] = (__bf16)htv[i];
        h_h[rowb + (size_t)i * 512]  = (__bf16)hreg[i];
      }
    }
    ++bar; group_barrier(flags_g, cw, bar, dead);
    stage(hx_g);
    __syncthreads();
  }
  if (owner) {
    #pragma unroll
    for (int i = 0; i < 4; ++i) {
      int b = g * 16 + q * 4 + i;
      dout[O_HT + (size_t)b * 512 + colc] = hreg[i];
    }
  }
}

// =========================== K3a: logits/softmax/error ===========================
__global__ void k3a_soft(const float* __restrict__ Woutw, const float* __restrict__ Woutb,
                         const int* __restrict__ y, float* __restrict__ dout,
                         float* __restrict__ errw)
{
  const int b = blockIdx.x, o = threadIdx.x;
  const float* hrow = dout + O_HT + (size_t)b * 512;
  float sv = Woutb[o];
  for (int k = 0; k < 512; ++k) sv += hrow[k] * Woutw[(size_t)o * 512 + k];
  float mx = sv;
  for (int off = 32; off; off >>= 1) mx = fmaxf(mx, __shfl_xor(mx, off, 64));
  float e = expf(sv - mx);
  float sum = e;
  for (int off = 32; off; off >>= 1) sum += __shfl_xor(sum, off, 64);
  float outp = e / sum;
  float errv = outp - ((y[b] == o) ? 1.f : 0.f);
  dout[O_OUT + b * 64 + o] = outp;
  dout[O_ERR + b * 64 + o] = errv;
  errw[b * 64 + o] = errv;
}

// =========================== K3b: 6 DFA projections ===========================
__global__ __launch_bounds__(256)
void k3b_proj(const float* __restrict__ err,
              const float* b0, const float* b1, const float* b2,
              const float* b3, const float* b4, const float* b5,
              float* __restrict__ proj)
{
  const int p = blockIdx.y;
  const int hb = blockIdx.x * 64;
  const float* BX = (p==0)?b0:(p==1)?b1:(p==2)?b2:(p==3)?b3:(p==4)?b4:b5;
  __shared__ float es[64 * 64];
  __shared__ float bs[64 * 65];
  for (int i = threadIdx.x; i < 4096; i += 256) es[i] = err[i];
  for (int i = threadIdx.x; i < 4096; i += 256) {
    int o = i >> 6, hh = i & 63;
    bs[o * 65 + hh] = BX[(size_t)o * 512 + hb + hh];
  }
  __syncthreads();
  for (int e = 0; e < 16; ++e) {
    int idx = threadIdx.x + e * 256;
    int b = idx >> 6, hh = idx & 63;
    float s = 0.f;
    for (int o = 0; o < 64; ++o) s += es[b * 64 + o] * bs[o * 65 + hh];
    proj[(size_t)p * 32768 + b * 512 + hb + hh] = s;
  }
}

// =========================== E1T: HpT / RsHpT m-major [512][TB] ===========================
__global__ __launch_bounds__(256)
void e1t(const __bf16* __restrict__ r_h, const __bf16* __restrict__ h_h,
         __bf16* __restrict__ HpT, __bf16* __restrict__ RsHpT)
{
  const int t = blockIdx.y, hb = blockIdx.x * 64;
  const int tid = threadIdx.x;
  __shared__ __bf16 tr[64 * 68];
  float hpv[16], rv[16];
  #pragma unroll
  for (int e = 0; e < 16; ++e) {
    int idx = tid + e * 256;
    int b = idx >> 6, hl = idx & 63;
    hpv[e] = hprev_at(h_h, t * 64 + b, hb + hl);
    rv[e]  = (float)r_h[((size_t)t * 64 + b) * 512 + hb + hl];
  }
  for (int rnd = 0; rnd < 2; ++rnd) {
    __syncthreads();
    #pragma unroll
    for (int e = 0; e < 16; ++e) {
      int idx = tid + e * 256;
      int b = idx >> 6, hl = idx & 63;
      tr[b * 68 + hl] = (__bf16)(rnd == 0 ? hpv[e] : rv[e] * hpv[e]);
    }
    __syncthreads();
    __bf16* dst = (rnd == 0) ? HpT : RsHpT;
    #pragma unroll
    for (int e = 0; e < 16; ++e) {
      int idx = tid + e * 256;
      int hl2 = idx >> 6, b2 = idx & 63;
      dst[(size_t)(hb + hl2) * TBc + t * 64 + b2] = tr[b2 * 68 + hl2];
    }
  }
}

// =========================== K4: P = (G @ W1^T) * mul, G fused, m-major out ==========
__global__ __launch_bounds__(256)
void k4_pgemm(const __bf16* __restrict__ z_h, const __bf16* __restrict__ ht_h,
              const __bf16* __restrict__ r_h, const __bf16* __restrict__ h_h,
              const float* __restrict__ proj, const __bf16* __restrict__ W1b,
              __bf16* __restrict__ P)
{
  const int p = blockIdx.z;
  const int krow0 = blockIdx.x * 128;
  const int n0 = blockIdx.y * 128;
  const int pidx = (p == 0) ? 5 : (p == 1) ? 4 : (p == 2) ? 1 : 0;
  const float* pr = proj + (size_t)pidx * 32768;
  const int tid = threadIdx.x, lane = tid & 63, wv = tid >> 6, q = lane >> 4;
  const int wm = (wv & 1) * 64, wn = (wv >> 1) * 64;
  __shared__ __align__(16) __bf16 Al[128 * 40];
  __shared__ __align__(16) __bf16 Bl[128 * 40];
  f32x4 acc[4][4] = {};
  for (int kt = 0; kt < 16; ++kt) {
    const int h0 = kt * 32;
    __syncthreads();
    #pragma unroll
    for (int e = 0; e < 4; ++e) {
      int idx = tid + e * 256;                 // 0..1023
      int row = idx >> 3, h4 = (idx & 7) * 4;
      int kg = krow0 + row;
      bf16x4 zz = *reinterpret_cast<const bf16x4*>(&z_h[(size_t)kg * 512 + h0 + h4]);
      bf16x4 tt = *reinterpret_cast<const bf16x4*>(&ht_h[(size_t)kg * 512 + h0 + h4]);
      float4 pv = *reinterpret_cast<const float4*>(&pr[(size_t)(kg & 63) * 512 + h0 + h4]);
      float pvv[4] = {pv.x, pv.y, pv.z, pv.w};
      bf16x4 gv;
      #pragma unroll
      for (int j = 0; j < 4; ++j) {
        float sz = 1.f - (float)zz[j];
        float v = pvv[j] * sz;
        if (p < 2) { float h = (float)tt[j]; v *= (1.f - h * h); }
        gv[j] = (__bf16)v;
      }
      *reinterpret_cast<bf16x4*>(&Al[row * 40 + h4]) = gv;
      bf16x4 wv4 = *reinterpret_cast<const bf16x4*>(&W1b[(size_t)(n0 + row) * 512 + h0 + h4]);
      *reinterpret_cast<bf16x4*>(&Bl[row * 40 + h4]) = wv4;
    }
    __syncthreads();
    bf16x8 af[4], bfv[4];
    #pragma unroll
    for (int mi = 0; mi < 4; ++mi)
      af[mi] = *reinterpret_cast<const bf16x8*>(&Al[(wm + mi * 16 + (lane & 15)) * 40 + q * 8]);
    #pragma unroll
    for (int ni = 0; ni < 4; ++ni)
      bfv[ni] = *reinterpret_cast<const bf16x8*>(&Bl[(wn + ni * 16 + (lane & 15)) * 40 + q * 8]);
    #pragma unroll
    for (int mi = 0; mi < 4; ++mi)
      #pragma unroll
      for (int ni = 0; ni < 4; ++ni)
        acc[mi][ni] = __builtin_amdgcn_mfma_f32_16x16x32_bf16(af[mi], bfv[ni], acc[mi][ni], 0, 0, 0);
  }
  __bf16* Pp = P + (size_t)p * THW;
  #pragma unroll
  for (int mi = 0; mi < 4; ++mi) {
    const int kg = krow0 + wm + mi * 16 + q * 4;
    const int tt = kg >> 6;
    #pragma unroll
    for (int ni = 0; ni < 4; ++ni) {
      const int n = n0 + wn + ni * 16 + (lane & 15);
      union { __bf16 b[4]; uint2 u; } pk;
      #pragma unroll
      for (int i = 0; i < 4; ++i) {
        float mul;
        if (p < 2) {
          float r = (float)r_h[(size_t)(kg + i) * 512 + n];
          float hp = 0.f;
          if (tt != 1) {
            int kr = (tt == 0) ? (16320 + (kg & 63) + i) : (kg + i - 128);
            hp = (float)h_h[(size_t)kr * 512 + n];
          }
          mul = hp * r * (1.f - r);
        } else {
          float h = (float)ht_h[(size_t)(kg + i) * 512 + n];
          mul = 1.f - h * h;
        }
        pk.b[i] = (__bf16)(acc[mi][ni][i] * mul);
      }
      *reinterpret_cast<uint2*>(&Pp[(size_t)n * TBc + kg]) = pk.u;
    }
  }
}

// =========================== K5: TN grad GEMM, split-k atomics into d_out ==========
__global__ __launch_bounds__(256)
void k5_grad(const __bf16* __restrict__ Ap, int amode, const __bf16* __restrict__ Bp,
             const __bf16* __restrict__ r_h, const __bf16* __restrict__ ht_h,
             const __bf16* __restrict__ h_h, const float* __restrict__ projA,
             float* __restrict__ out, int N, int klen, float scale)
{
  const int m0 = blockIdx.x * 128;
  const int n0 = blockIdx.y * 128;
  const int tid = threadIdx.x, lane = tid & 63, wv = tid >> 6, q = lane >> 4;
  const int wm = (wv & 1) * 64, wn = (wv >> 1) * 64;
  __shared__ __align__(16) __bf16 Al[128 * 72];
  __shared__ __align__(16) __bf16 Bl[128 * 72];
  f32x4 acc[4][4] = {};
  const int iters = klen >> 6;
  for (int kt = 0; kt < iters; ++kt) {
    const int kk0 = blockIdx.z * klen + kt * 64;
    __syncthreads();
    #pragma unroll
    for (int e = 0; e < 8; ++e) {
      int idx = tid + e * 256;              // 0..2047
      int row = idx >> 4, c4 = (idx & 15) * 4;
      bf16x4 bv = *reinterpret_cast<const bf16x4*>(&Bp[(size_t)(n0 + row) * TBc + kk0 + c4]);
      *reinterpret_cast<bf16x4*>(&Bl[row * 72 + c4]) = bv;
    }
    if (amode == 0) {
      #pragma unroll
      for (int e = 0; e < 8; ++e) {
        int idx = tid + e * 256;
        int row = idx >> 4, c4 = (idx & 15) * 4;
        bf16x4 av = *reinterpret_cast<const bf16x4*>(&Ap[(size_t)(m0 + row) * TBc + kk0 + c4]);
        *reinterpret_cast<bf16x4*>(&Al[row * 72 + c4]) = av;
      }
    } else {
      #pragma unroll
      for (int e = 0; e < 8; ++e) {
        int idx = tid + e * 256;
        int kk = idx >> 5;                  // 0..63 local k row
        int m4 = (idx & 31) * 4;
        int kg = kk0 + kk;
        int tt = kg >> 6;
        bf16x4 hs = *reinterpret_cast<const bf16x4*>(&ht_h[(size_t)kg * 512 + m0 + m4]);
        bf16x4 rv = *reinterpret_cast<const bf16x4*>(&r_h[(size_t)kg * 512 + m0 + m4]);
        float4 pv = *reinterpret_cast<const float4*>(&projA[(size_t)(kg & 63) * 512 + m0 + m4]);
        float pvv[4] = {pv.x, pv.y, pv.z, pv.w};
        float hpf[4] = {0.f, 0.f, 0.f, 0.f};
        if (tt != 1) {
          int kr = (tt == 0) ? (16320 + (kg & 63)) : (kg - 128);
          bf16x4 hp = *reinterpret_cast<const bf16x4*>(&h_h[(size_t)kr * 512 + m0 + m4]);
          #pragma unroll
          for (int j = 0; j < 4; ++j) hpf[j] = (float)hp[j];
        }
        #pragma unroll
        for (int j = 0; j < 4; ++j) {
          float r = (float)rv[j];
          float zg = (hpf[j] - (float)hs[j]) * r * (1.f - r) * pvv[j];
          Al[(m4 + j) * 72 + kk] = (__bf16)zg;
        }
      }
    }
    __syncthreads();
    #pragma unroll
    for (int ks = 0; ks < 2; ++ks) {
      bf16x8 af[4], bfv[4];
      #pragma unroll
      for (int mi = 0; mi < 4; ++mi)
        af[mi] = *reinterpret_cast<const bf16x8*>(&Al[(wm + mi * 16 + (lane & 15)) * 72 + ks * 32 + q * 8]);
      #pragma unroll
      for (int ni = 0; ni < 4; ++ni)
        bfv[ni] = *reinterpret_cast<const bf16x8*>(&Bl[(wn + ni * 16 + (lane & 15)) * 72 + ks * 32 + q * 8]);
      #pragma unroll
      for (int mi = 0; mi < 4; ++mi)
        #pragma unroll
        for (int ni = 0; ni < 4; ++ni)
          acc[mi][ni] = __builtin_amdgcn_mfma_f32_16x16x32_bf16(af[mi], bfv[ni], acc[mi][ni], 0, 0, 0);
    }
  }
  #pragma unroll
  for (int mi = 0; mi < 4; ++mi) {
    const int m = m0 + wm + mi * 16 + q * 4;
    #pragma unroll
    for (int ni = 0; ni < 4; ++ni) {
      const int n = n0 + wn + ni * 16 + (lane & 15);
      #pragma unroll
      for (int i = 0; i < 4; ++i)
        atomicAdd(&out[(size_t)(m + i) * N + n], acc[mi][ni][i] * scale);
    }
  }
}

// =========================== db kernels ===========================
// merged: y=0 -> P-plane 2 (HV) into db[0..511]; y=1 -> P-plane 0 (AV) into db[1024..1535]
__global__ void k_dbP(const __bf16* __restrict__ P, float* __restrict__ db)
{
  const size_t plane = (blockIdx.y == 0) ? 2 : 0;
  const int dbo = (blockIdx.y == 0) ? 0 : 1024;
  const __bf16* row = P + plane * THW + (size_t)blockIdx.x * TBc;
  float sv = 0.f;
  for (int i = threadIdx.x; i < TBc; i += 256) sv += (float)row[i];
  for (int off = 32; off; off >>= 1) sv += __shfl_xor(sv, off, 64);
  __shared__ float red[4];
  if ((threadIdx.x & 63) == 0) red[threadIdx.x >> 6] = sv;
  __syncthreads();
  if (threadIdx.x == 0)
    atomicAdd(&db[dbo + blockIdx.x], (red[0] + red[1] + red[2] + red[3]) * (1.f / 64.f));
}

__global__ void k_dbzg(const __bf16* __restrict__ r_h, const __bf16* __restrict__ ht_h,
                       const __bf16* __restrict__ h_h, const float* __restrict__ proj,
                       float* __restrict__ db)
{
  const int hb = blockIdx.x * 64;
  const int col = hb + (threadIdx.x & 63);
  const int part = threadIdx.x >> 6;
  const int kb = blockIdx.y * 1024;
  float sum = 0.f;
  for (int k = kb + part; k < kb + 1024; k += 4) {
    float hs = (float)ht_h[(size_t)k * 512 + col];
    float r  = (float)r_h[(size_t)k * 512 + col];
    float hp = hprev_at(h_h, k, col);
    float pv = proj[3 * 32768 + (size_t)(k & 63) * 512 + col];
    sum += (hp - hs) * r * (1.f - r) * pv;
  }
  __shared__ float sred[4][64];
  sred[part][threadIdx.x & 63] = sum;
  __syncthreads();
  if (threadIdx.x < 64)
    atomicAdd(&db[512 + hb + threadIdx.x],
              (sred[0][threadIdx.x] + sred[1][threadIdx.x] +
               sred[2][threadIdx.x] + sred[3][threadIdx.x]) * (1.f / 64.f));
}

// =========================== K6: norm + clip (grads live in d_out) ===========================
__global__ void k6a_sumsq(const float* __restrict__ dout, const float* __restrict__ db,
                          float* __restrict__ slots)
{
  const int yy = blockIdx.y;
  const float* src; int count;
  if (yy < 3)      { src = dout + O_DW0 + (size_t)yy * 262144; count = 262144; }
  else if (yy < 6) { src = dout + O_DV0 + (size_t)(yy - 3) * 65536; count = 65536; }
  else             { src = db + (size_t)(yy - 6) * 512; count = 512; }
  int start = blockIdx.x * 4096;
  if (start >= count) return;
  int end = min(start + 4096, count);
  float sp = 0.f;
  for (int i = start + threadIdx.x; i < end; i += 256) { float v = src[i]; sp += v * v; }
  for (int off = 32; off; off >>= 1) sp += __shfl_xor(sp, off, 64);
  __shared__ float red[4];
  if ((threadIdx.x & 63) == 0) red[threadIdx.x >> 6] = sp;
  __syncthreads();
  if (threadIdx.x == 0) atomicAdd(&slots[yy], red[0] + red[1] + red[2] + red[3]);
}

__global__ void k6b_write(const float* __restrict__ db,
                          const float* __restrict__ slots, float* __restrict__ dout)
{
  const int yy = blockIdx.y;
  const float* src; int count; size_t oo;
  if (yy < 3)      { oo = O_DW0 + (size_t)yy * 262144; src = dout + oo; count = 262144; }
  else if (yy < 6) { oo = O_DV0 + (size_t)(yy - 3) * 65536; src = dout + oo; count = 65536; }
  else             { oo = O_DB0 + (size_t)(yy - 6) * 512; src = db + (size_t)(yy - 6) * 512; count = 512; }
  int start = blockIdx.x * 4096;
  if (start >= count) return;
  int end = min(start + 4096, count);
  float inv = 1.f / sqrtf(slots[yy]);
  for (int i = start + threadIdx.x; i < end; i += 256) {
    float v = src[i] * inv;
    dout[oo + i] = fminf(fmaxf(v, -5.f), 5.f);
  }
}

// =========================== launch ===========================
extern "C" void kernel_launch(void* const* d_in, const int* in_sizes, int n_in,
                              void* d_out, int out_size, void* d_ws, size_t ws_size,
                              hipStream_t stream)
{
  const float* x     = (const float*)d_in[0];
  const int*   y     = (const int*)d_in[1];
  const float* W1w   = (const float*)d_in[2];
  const float* V1w   = (const float*)d_in[3];
  const float* V1b   = (const float*)d_in[4];
  const float* W2w   = (const float*)d_in[5];
  const float* W2b   = (const float*)d_in[6];
  const float* V2w   = (const float*)d_in[7];
  const float* W3w   = (const float*)d_in[8];
  const float* W3b   = (const float*)d_in[9];
  const float* V3w   = (const float*)d_in[10];
  const float* Woutw = (const float*)d_in[11];
  const float* Woutb = (const float*)d_in[12];
  const float* BW1   = (const float*)d_in[13];
  const float* BV1   = (const float*)d_in[14];
  const float* BW2   = (const float*)d_in[15];
  const float* BV2   = (const float*)d_in[16];
  const float* BW3   = (const float*)d_in[17];
  const float* BV3   = (const float*)d_in[18];
  float* dout = (float*)d_out;
  char* ws = (char*)d_ws;

  if (ws_size < W_NEED) { ksent<<<1, 1, 0, stream>>>(dout, (float)ws_size); return; }

  float*  slots = (float*)(ws + W_SLOT);
  float*  dbr   = (float*)(ws + W_DB);
  int*    flg   = (int*)(ws + W_FLG);
  float*  errw  = (float*)(ws + W_ERRW);
  float*  proj  = (float*)(ws + W_PROJ);
  __bf16* W1b   = (__bf16*)(ws + W_W1B);
  float*  hx    = (float*)(ws + W_HX);
  float*  hrx   = (float*)(ws + W_HRX);
  __bf16* XT    = (__bf16*)(ws + W_XT);
  __bf16* r_h   = (__bf16*)(ws + W_HIST);
  __bf16* z_h   = (__bf16*)(ws + W_HIST + 16777216);
  __bf16* ht_h  = (__bf16*)(ws + W_HIST + 33554432);
  __bf16* h_h   = (__bf16*)(ws + W_HIST + 50331648);
  char*   PB    = ws + W_PB;

  // xV fp32 (dead after k2) aliases P/HpT/RsHpT (live after k2)
  float* xv1 = (float*)PB;
  float* xv2 = (float*)(PB + 33554432);
  float* xv3 = (float*)(PB + 67108864);
  __bf16* P     = (__bf16*)PB;                     // 4 x [512][TB] bf16 = 67.1 MB
  __bf16* HpT   = (__bf16*)(PB + 67108864);
  __bf16* RsHpT = (__bf16*)(PB + 83886080);

  kzero<<<16, 256, 0, stream>>>((float*)ws, 4096);                  // ctr+slots+dbr+flags
  kzero<<<3840, 256, 0, stream>>>(dout + O_DW0, 983040);            // grad accumulators
  k0_cast<<<1024, 256, 0, stream>>>(W1w, W1b, 262144);
  k1_xv<<<dim3(24, 256), 256, 0, stream>>>(x, V1w, V2w, V3w, V1b, W2b, W3b, xv1, xv2, xv3);
  e0_xt<<<256, 256, 0, stream>>>(x, XT);
  k2_recur<<<64, 256, 0, stream>>>(W1w, W2w, W3w, xv1, xv2, xv3,
                                   r_h, z_h, ht_h, h_h, hx, hrx, flg, dout);
  k3a_soft<<<64, 64, 0, stream>>>(Woutw, Woutb, y, dout, errw);
  k3b_proj<<<dim3(8, 6), 256, 0, stream>>>(errw, BW1, BV1, BW2, BV2, BW3, BV3, proj);
  e1t<<<dim3(8, 256), 256, 0, stream>>>(r_h, h_h, HpT, RsHpT);
  k_dbzg<<<dim3(8, 16), 256, 0, stream>>>(r_h, ht_h, h_h, proj, dbr);   // db1

  k4_pgemm<<<dim3(128, 4, 4), 256, 0, stream>>>(z_h, ht_h, r_h, h_h, proj, W1b, P);
  const float sc = 1.f / 64.f;
  // dW0 = HW^T @ RsHp ; dW1 = zgW^T @ Hp ; dW2 = AW^T @ Hp
  k5_grad<<<dim3(4, 4, 16), 256, 0, stream>>>(P + 3 * THW, 0, RsHpT, r_h, ht_h, h_h, proj,
                                              dout + O_DW0, 512, 1024, sc);
  k5_grad<<<dim3(4, 4, 16), 256, 0, stream>>>(nullptr, 1, HpT, r_h, ht_h, h_h, proj + 2 * 32768,
                                              dout + O_DW0 + 262144, 512, 1024, sc);
  k5_grad<<<dim3(4, 4, 16), 256, 0, stream>>>(P + 1 * THW, 0, HpT, r_h, ht_h, h_h, proj,
                                              dout + O_DW0 + 524288, 512, 1024, sc);
  // dV0 = HV^T @ X ; dV1 = zgV^T @ X ; dV2 = AV^T @ X
  k5_grad<<<dim3(4, 1, 16), 256, 0, stream>>>(P + 2 * THW, 0, XT, r_h, ht_h, h_h, proj,
                                              dout + O_DV0, 128, 1024, sc);
  k5_grad<<<dim3(4, 1, 16), 256, 0, stream>>>(nullptr, 1, XT, r_h, ht_h, h_h, proj + 3 * 32768,
                                              dout + O_DV0 + 65536, 128, 1024, sc);
  k5_grad<<<dim3(4, 1, 16), 256, 0, stream>>>(P + 0 * THW, 0, XT, r_h, ht_h, h_h, proj,
                                              dout + O_DV0 + 131072, 128, 1024, sc);
  k_dbP<<<dim3(512, 2), 256, 0, stream>>>(P, dbr);             // db0 (HV) + db2 (AV)
  k6a_sumsq<<<dim3(64, 9), 256, 0, stream>>>(dout, dbr, slots);
  k6b_write<<<dim3(64, 9), 256, 0, stream>>>(dbr, slots, dout);
}